// Round 8
// baseline (2061.368 us; speedup 1.0000x reference)
//
#include <hip/hip_runtime.h>
#include <hip/hip_cooperative_groups.h>
#include <math.h>

namespace cg = cooperative_groups;

// ---------------------------------------------------------------------------
// conv1: x[512][1][64][64] -> relu -> maxpool2 -> a1[512][16][32][32]
__global__ void k_conv1(const float* __restrict__ x, const float* __restrict__ w,
                        const float* __restrict__ bias, float* __restrict__ out) {
  int idx = blockIdx.x * 256 + threadIdx.x;
  int ox = idx & 31, oy = (idx >> 5) & 31, oc = (idx >> 10) & 15, n = idx >> 14;
  const float* im = x + n * 4096;
  float wv[9];
#pragma unroll
  for (int i = 0; i < 9; ++i) wv[i] = w[oc * 9 + i];
  float bs = bias[oc];
  float m = 0.f;
#pragma unroll
  for (int dy = 0; dy < 2; ++dy)
#pragma unroll
    for (int dx = 0; dx < 2; ++dx) {
      int cy = oy * 2 + dy, cx = ox * 2 + dx;
      float s = bs;
#pragma unroll
      for (int ky = 0; ky < 3; ++ky) {
        int yy = cy + ky - 1;
        if (yy < 0 || yy >= 64) continue;
#pragma unroll
        for (int kx = 0; kx < 3; ++kx) {
          int xx = cx + kx - 1;
          if (xx < 0 || xx >= 64) continue;
          s += im[yy * 64 + xx] * wv[ky * 3 + kx];
        }
      }
      m = fmaxf(m, fmaxf(s, 0.f));
    }
  out[idx] = m;
}

// ---------------------------------------------------------------------------
// weight prep: w2t[c][tap][32oc], w3t[c][tap][256oc]
__global__ void k_prep_w(const float* __restrict__ w2, float* __restrict__ w2t,
                         const float* __restrict__ w3, float* __restrict__ w3t) {
  int id = blockIdx.x * 256 + threadIdx.x;
  if (id < 73728) {
    int ct = id >> 8, oc = id & 255;
    int c = ct / 9, tap = ct - 9 * c;
    w3t[id] = w3[(oc * 32 + c) * 9 + tap];
  }
  if (id < 4608) {
    int ct = id >> 5, oc = id & 31;
    int c = ct / 9, tap = ct - 9 * c;
    w2t[id] = w2[(oc * 16 + c) * 9 + tap];
  }
}

// ---------------------------------------------------------------------------
// conv2: a1[512][16][32][32] -> relu -> maxpool2 -> a2[n][px=256][oc=32]
__global__ __launch_bounds__(256) void k_conv2(
    const float* __restrict__ a1, const float* __restrict__ w2t,
    const float* __restrict__ bias, float* __restrict__ a2) {
  __shared__ __align__(16) float ins[8 * 1024];
  int n = blockIdx.x, ocg = blockIdx.y;
  int tid = threadIdx.x;
  int py = tid >> 4, px = tid & 15;
  int y0 = 2 * py - 1, x0 = 2 * px - 1;
  float acc[16][4] = {};
  const float* wb = w2t + ocg * 16;
  for (int ph = 0; ph < 2; ++ph) {
    __syncthreads();
    const float4* src = (const float4*)(a1 + n * 16384 + ph * 8192);
    for (int i = tid; i < 2048; i += 256) ((float4*)ins)[i] = src[i];
    __syncthreads();
    for (int c = 0; c < 8; ++c) {
      float wv[4][4];
#pragma unroll
      for (int r = 0; r < 4; ++r) {
        int y = y0 + r;
        bool vy = (y >= 0) && (y < 32);
        int yc = vy ? y : 0;
#pragma unroll
        for (int cc = 0; cc < 4; ++cc) {
          int xx = x0 + cc;
          bool vx = (xx >= 0) && (xx < 32);
          int xc = vx ? xx : 0;
          float t = ins[c * 1024 + yc * 32 + xc];
          wv[r][cc] = (vy && vx) ? t : 0.f;
        }
      }
      int ch = ph * 8 + c;
#pragma unroll
      for (int ky = 0; ky < 3; ++ky)
#pragma unroll
        for (int kx = 0; kx < 3; ++kx) {
          const float* w16 = wb + (ch * 9 + ky * 3 + kx) * 32;
#pragma unroll
          for (int i = 0; i < 4; ++i) {
            float vv = wv[(i >> 1) + ky][(i & 1) + kx];
#pragma unroll
            for (int j = 0; j < 16; ++j) acc[j][i] += vv * w16[j];
          }
        }
    }
  }
  const float* bp = bias + ocg * 16;
  float4 o[4];
#pragma unroll
  for (int j = 0; j < 16; ++j) {
    float m = fmaxf(fmaxf(acc[j][0], acc[j][1]), fmaxf(acc[j][2], acc[j][3]));
    ((float*)o)[j] = fmaxf(m + bp[j], 0.f);
  }
  float4* dst = (float4*)(a2 + (size_t)(n * 256 + tid) * 32 + ocg * 16);
#pragma unroll
  for (int q = 0; q < 4; ++q) dst[q] = o[q];
}

// ---------------------------------------------------------------------------
// conv3 v6: a2[n][px][32ch] -> relu -> mean(HW) -> comb0[t][ch][b]
// Static acc indices (rule #20 fix for round-6's 251MB scratch spill):
// i = dr - ky with ky unrolled -> every acc[i][j] literal -> registers.
__global__ __launch_bounds__(512, 4) void k_conv3(
    const float* __restrict__ a2, const float* __restrict__ w3t,
    const float* __restrict__ bias, float* __restrict__ comb0) {
  __shared__ __align__(16) float ins[324 * 20];  // 25,920 B
  float4* ins4 = (float4*)ins;
  int n = blockIdx.x, ocb = blockIdx.y;
  int tid = threadIdx.x;
  for (int i = tid; i < 1620; i += 512) ins4[i] = float4{0.f, 0.f, 0.f, 0.f};
  int wvid = __builtin_amdgcn_readfirstlane(tid >> 6);  // 8 waves
  int lane = tid & 63;
  int tr = lane >> 4, tc = lane & 15;
  float acc[4][16] = {};
  const float* wbase = w3t + ocb * 128 + wvid * 16;
  const float4* src = (const float4*)(a2 + (size_t)n * 8192);
  for (int hf = 0; hf < 2; ++hf) {
    __syncthreads();
    for (int i = tid; i < 1024; i += 512) {
      int px = i >> 2, cg = i & 3;
      int p = ((px >> 4) + 1) * 18 + (px & 15) + 1;
      ins4[p * 5 + cg] = src[px * 8 + hf * 4 + cg];
    }
    __syncthreads();
    for (int cg = 0; cg < 4; ++cg) {
      int chb = hf * 16 + cg * 4;
#pragma unroll
      for (int dr = 0; dr < 6; ++dr) {
#pragma unroll
        for (int dc = 0; dc < 3; ++dc) {
          int pp = (4 * tr + dr) * 18 + tc + dc;
          float4 v = ins4[pp * 5 + cg];
#pragma unroll
          for (int c = 0; c < 4; ++c) {
            float vv = ((const float*)&v)[c];
#pragma unroll
            for (int ky = 0; ky < 3; ++ky) {
              int i = dr - ky;             // literal after unroll
              if (i >= 0 && i < 4) {
                const float* w16 = wbase + (((chb + c) * 9 + ky * 3 + dc) * 256);
#pragma unroll
                for (int j = 0; j < 16; ++j) acc[i][j] += vv * w16[j];
              }
            }
          }
        }
      }
    }
  }
  const float* bp = bias + ocb * 128 + wvid * 16;
  int bb = n >> 4, tt = n & 15;
#pragma unroll
  for (int j = 0; j < 16; ++j) {
    float bj = bp[j];
    float s = 0.f;
#pragma unroll
    for (int i = 0; i < 4; ++i) s += fmaxf(acc[i][j] + bj, 0.f);
#pragma unroll
    for (int off = 32; off; off >>= 1) s += __shfl_down(s, off, 64);
    if (lane == 0) {
      int oc = ocb * 128 + wvid * 16 + j;
      comb0[(size_t)(tt * 768 + oc) * 32 + bb] = s * (1.f / 256.f);
    }
  }
}

// ---------------------------------------------------------------------------
// weight transpose: W[fan][512] -> WT[512][fan], 8 arrays in one launch
struct TPtrs { const float* in[8]; float* out[8]; };

__global__ void k_transpose(TPtrs p) {
  __shared__ float tile[32][33];
  int z = blockIdx.z;
  int fan = (z < 4) ? 768 : 1024;
  int k0 = blockIdx.x * 32, h0 = blockIdx.y * 32;
  if (k0 >= fan) return;
  const float* in = p.in[z];
  float* out = p.out[z];
  int tx = threadIdx.x, ty = threadIdx.y;  // 32 x 8
  for (int r = 0; r < 32; r += 8)
    tile[ty + r][tx] = in[(k0 + ty + r) * 512 + h0 + tx];
  __syncthreads();
  for (int r = 0; r < 32; r += 8)
    out[(h0 + ty + r) * fan + k0 + tx] = tile[tx][ty + r];
}

// ---------------------------------------------------------------------------
// Cooperative LSTM v2: 256 blocks x 512 threads (1 block/CU ALWAYS fits ->
// coop launch cannot be rejected; round-7 lesson: 512 blocks needed VGPR<=128
// co-residency that was never guaranteed). Each block owns h = {2b, 2b+1},
// stages both layers' 8 gate rows to dynamic LDS once, c in registers,
// pipelines l0(t) || l1(t-1) with grid.sync().
// thread = (hs = tid>>8, c = (tid>>6)&3, kq = (tid>>2)&15, bq = tid&3);
// 8 batches/thread in registers; weight ds_read_b128 rotated by kq%QN so the
// stride-KT column collapse becomes <=2-way (free).
struct CoopArgs {
  float* comb0; float* comb1;
  const float* w00; const float* w01; const float* w02; const float* w03;
  const float* w10; const float* w11; const float* w12; const float* w13;
  const float* b00; const float* b01; const float* b02; const float* b03;
  const float* b10; const float* b11; const float* b12; const float* b13;
};

// dynamic LDS (floats): wl0 [0,6144) | wl1 [6144,14336) | gsum [14336,18944)
// | pre [18944,19208)  => 76,832 B
#define COOP_LDS_BYTES (19208 * 4)

template <int IN>
__device__ __forceinline__ void lstm_step2(
    int hbase, int tid, const float* __restrict__ comb,
    const float* __restrict__ wl,
    float* __restrict__ houtA, float* __restrict__ houtB,
    const float* __restrict__ Bf, const float* __restrict__ Bi,
    const float* __restrict__ Bg, const float* __restrict__ Bo,
    float& creg, float* __restrict__ gsum, float* __restrict__ pre) {
  constexpr int FAN = IN + 512;
  constexpr int KT = FAN / 16;   // k per thread
  constexpr int QN = KT / 4;     // float4 chunks per thread
  __syncthreads();
  const int hs = tid >> 8;
  const int c = (tid >> 6) & 3;
  const int kq = (tid >> 2) & 15;
  const int bq = tid & 3;
  const int kbase = kq * KT;
  const float4* w4 = (const float4*)(wl + (size_t)(hs * 4 + c) * FAN + kbase);
  const float4* a4 = (const float4*)comb;
  const int r = kq % QN;
  float acc0 = 0.f, acc1 = 0.f, acc2 = 0.f, acc3 = 0.f;
  float acc4 = 0.f, acc5 = 0.f, acc6 = 0.f, acc7 = 0.f;
#pragma unroll
  for (int kk = 0; kk < QN; ++kk) {
    int idx = kk + r;
    if (idx >= QN) idx -= QN;
    float4 w = w4[idx];
#pragma unroll
    for (int j = 0; j < 4; ++j) {
      float wj = ((const float*)&w)[j];
      int k8 = (kbase + idx * 4 + j) * 8;
      float4 a0 = a4[k8 + bq];
      float4 a1 = a4[k8 + 4 + bq];
      acc0 += wj * a0.x; acc1 += wj * a0.y; acc2 += wj * a0.z; acc3 += wj * a0.w;
      acc4 += wj * a1.x; acc5 += wj * a1.y; acc6 += wj * a1.z; acc7 += wj * a1.w;
    }
  }
  float4* grow = (float4*)(gsum + (size_t)((hs * 4 + c) * 16 + kq) * 36);
  grow[bq] = float4{acc0, acc1, acc2, acc3};       // batches 4bq..4bq+3
  grow[4 + bq] = float4{acc4, acc5, acc6, acc7};   // batches 16+4bq..
  __syncthreads();
  if (tid < 256) {
    int g = tid >> 5, b = tid & 31;  // g = hs*4+c
    float s = 0.f;
#pragma unroll
    for (int q = 0; q < 16; ++q) s += gsum[(size_t)(g * 16 + q) * 36 + b];
    pre[g * 33 + b] = s;
  }
  __syncthreads();
  if (tid < 64) {
    int hs2 = tid >> 5, b = tid & 31;
    int hh = hbase + hs2;
    float fp = pre[(hs2 * 4 + 0) * 33 + b] + Bf[hh];
    float ip = pre[(hs2 * 4 + 1) * 33 + b] + Bi[hh];
    float gp = pre[(hs2 * 4 + 2) * 33 + b] + Bg[hh];
    float op = pre[(hs2 * 4 + 3) * 33 + b] + Bo[hh];
    float ft = 1.f / (1.f + expf(-fp));
    float it_ = 1.f / (1.f + expf(-ip));
    float gt = tanhf(gp);
    float ot = 1.f / (1.f + expf(-op));
    float cn = ft * creg + it_ * gt;
    creg = cn;
    float hn = ot * tanhf(cn);
    houtA[hh * 32 + b] = hn;
    houtB[hh * 32 + b] = hn;
  }
}

__global__ __launch_bounds__(512) void k_lstm_coop(CoopArgs A) {
  extern __shared__ float smem[];
  float* wl0 = smem;
  float* wl1 = smem + 6144;
  float* gsum = smem + 14336;
  float* pre = smem + 18944;
  const int tid = threadIdx.x;
  const int hbase = blockIdx.x * 2;
  {
    const float* s0[4] = {A.w00, A.w01, A.w02, A.w03};
    const float* s1[4] = {A.w10, A.w11, A.w12, A.w13};
    for (int i = tid; i < 1536; i += 512) {
      int hs = i / 768, rem = i - hs * 768;
      int g = rem / 192, q = rem - g * 192;
      ((float4*)(wl0 + (size_t)(hs * 4 + g) * 768))[q] =
          ((const float4*)(s0[g] + (size_t)(hbase + hs) * 768))[q];
    }
    for (int i = tid; i < 2048; i += 512) {
      int hs = i >> 10, rem = i & 1023;
      int g = rem >> 8, q = rem & 255;
      ((float4*)(wl1 + (size_t)(hs * 4 + g) * 1024))[q] =
          ((const float4*)(s1[g] + (size_t)(hbase + hs) * 1024))[q];
    }
  }
  float c0reg = 0.f, c1reg = 0.f;
  const int C0 = 768 * 32, C1 = 1024 * 32;
  cg::grid_group grid = cg::this_grid();
  for (int it = 0; it <= 16; ++it) {
    if (it < 16)
      lstm_step2<256>(hbase, tid, A.comb0 + (size_t)it * C0, wl0,
                      A.comb0 + (size_t)(it + 1) * C0 + 256 * 32,
                      A.comb1 + (size_t)it * C1,
                      A.b00, A.b01, A.b02, A.b03, c0reg, gsum, pre);
    if (it >= 1)
      lstm_step2<512>(hbase, tid, A.comb1 + (size_t)(it - 1) * C1, wl1,
                      A.comb1 + (size_t)it * C1 + 512 * 32,
                      A.comb1 + (size_t)it * C1 + 512 * 32,
                      A.b10, A.b11, A.b12, A.b13, c1reg, gsum, pre);
    if (it < 16) {
      __threadfence();
      grid.sync();
    }
  }
}

// ---------------------------------------------------------------------------
// Fallback LSTM (round-5/6 proven): used only if coop launch is rejected.
struct LstmArgs {
  const float* comb; float* houtA; float* houtB; float* cT;
  const float* Wf; const float* Wi; const float* Wg; const float* Wo;
  const float* bf; const float* bi; const float* bg; const float* bo;
};

template <int IN>
__device__ __forceinline__ void lstm_body(int h, int tid, const LstmArgs& A,
                                          float* wl, float* gsum, float* pre) {
  constexpr int FAN = IN + 512;
  constexpr int PR = FAN + 4;
  constexpr int KT = FAN / 16;
  if (tid < FAN / 4) {
    ((float4*)(wl + 0 * PR))[tid] = ((const float4*)(A.Wf + (size_t)h * FAN))[tid];
    ((float4*)(wl + 1 * PR))[tid] = ((const float4*)(A.Wi + (size_t)h * FAN))[tid];
    ((float4*)(wl + 2 * PR))[tid] = ((const float4*)(A.Wg + (size_t)h * FAN))[tid];
    ((float4*)(wl + 3 * PR))[tid] = ((const float4*)(A.Wo + (size_t)h * FAN))[tid];
  }
  __syncthreads();
  const int kq = (tid >> 3) & 15, c = tid >> 7, bq = tid & 7;
  const int kbase = kq * KT;
  const float4* w4 = (const float4*)(wl + c * PR + kbase);
  const float4* a4 = (const float4*)A.comb + bq;
  float acc0 = 0.f, acc1 = 0.f, acc2 = 0.f, acc3 = 0.f;
#pragma unroll
  for (int kk = 0; kk < KT / 4; ++kk) {
    float4 w = w4[kk];
#pragma unroll
    for (int j = 0; j < 4; ++j) {
      float wj = ((const float*)&w)[j];
      float4 a = a4[(size_t)(kbase + kk * 4 + j) * 8];
      acc0 += wj * a.x; acc1 += wj * a.y; acc2 += wj * a.z; acc3 += wj * a.w;
    }
  }
  ((float4*)(gsum + (c * 16 + kq) * 36))[bq] = float4{acc0, acc1, acc2, acc3};
  __syncthreads();
  if (tid < 128) {
    int cc = tid >> 5, b = tid & 31;
    float s = 0.f;
#pragma unroll
    for (int q = 0; q < 16; ++q) s += gsum[(cc * 16 + q) * 36 + b];
    pre[cc * 33 + b] = s;
  }
  __syncthreads();
  if (tid < 32) {
    int b = tid;
    float fp = pre[b] + A.bf[h];
    float ip = pre[33 + b] + A.bi[h];
    float gp = pre[66 + b] + A.bg[h];
    float op = pre[99 + b] + A.bo[h];
    float ft = 1.f / (1.f + expf(-fp));
    float it_ = 1.f / (1.f + expf(-ip));
    float gt = tanhf(gp);
    float ot = 1.f / (1.f + expf(-op));
    float cn = ft * A.cT[h * 32 + b] + it_ * gt;
    A.cT[h * 32 + b] = cn;
    float hn = ot * tanhf(cn);
    A.houtA[h * 32 + b] = hn;
    A.houtB[h * 32 + b] = hn;
  }
}

template <int IN>
__global__ __launch_bounds__(512) void k_lstm(LstmArgs a) {
  __shared__ __align__(16) float wl[4 * 1028];
  __shared__ __align__(16) float gsum[4 * 16 * 36];
  __shared__ float pre[4 * 33];
  lstm_body<IN>(blockIdx.x, threadIdx.x, a, wl, gsum, pre);
}

__global__ __launch_bounds__(512) void k_lstm_pair(LstmArgs a0, LstmArgs a1) {
  __shared__ __align__(16) float wl[4 * 1028];
  __shared__ __align__(16) float gsum[4 * 16 * 36];
  __shared__ float pre[4 * 33];
  if (blockIdx.x < 512)
    lstm_body<256>(blockIdx.x, threadIdx.x, a0, wl, gsum, pre);
  else
    lstm_body<512>(blockIdx.x - 512, threadIdx.x, a1, wl, gsum, pre);
}

// ---------------------------------------------------------------------------
// classifier: input h1T layout [h][b] (a comb slice)
__global__ void k_cls(const float* __restrict__ h1T, const float* __restrict__ cw1,
                      const float* __restrict__ cb1, const float* __restrict__ cw2,
                      const float* __restrict__ cb2, const float* __restrict__ cw3,
                      const float* __restrict__ cb3, float* __restrict__ out) {
  __shared__ float hv[512];
  __shared__ float y1[128];
  __shared__ float y2[64];
  int b = blockIdx.x, tid = threadIdx.x;
  for (int i = tid; i < 512; i += 128) hv[i] = h1T[i * 32 + b];
  __syncthreads();
  float s = cb1[tid];
  for (int k = 0; k < 512; ++k) s += hv[k] * cw1[k * 128 + tid];
  y1[tid] = fmaxf(s, 0.f);
  __syncthreads();
  if (tid < 64) {
    float s2 = cb2[tid];
    for (int k = 0; k < 128; ++k) s2 += y1[k] * cw2[k * 64 + tid];
    y2[tid] = fmaxf(s2, 0.f);
  }
  __syncthreads();
  if (tid < 6) {
    float s3 = cb3[tid];
    for (int k = 0; k < 64; ++k) s3 += y2[k] * cw3[k * 6 + tid];
    out[b * 6 + tid] = s3;
  }
}

// ---------------------------------------------------------------------------
// Workspace (floats):
//  region0 [0..8,388,608) = a1 (conv1 out, dead after conv2); then reused:
//    wt    @ 0          [3,670,016]
//    comb0 @ 3,670,016  [17*768*32  = 417,792]   comb0[t] = [emb(t), h0(t-1)]
//    comb1 @ 4,087,808  [17*1024*32 = 557,056]   comb1[t] = [h0(t), h1(t-1)]
//    c0    @ 4,644,864  [16,384];  c1 @ 4,661,248 [16,384]  (fallback only)
//  a2  @ 8,388,608  [4,194,304]   layout [n][px][oc]
//  w2t @ 12,582,912 [4,608];  w3t @ 12,587,520 [73,728]
extern "C" void kernel_launch(void* const* d_in, const int* in_sizes, int n_in,
                              void* d_out, int out_size, void* d_ws, size_t ws_size,
                              hipStream_t stream) {
  const float* x  = (const float*)d_in[0];
  const float* w1 = (const float*)d_in[1];
  const float* b1 = (const float*)d_in[2];
  const float* w2 = (const float*)d_in[3];
  const float* b2 = (const float*)d_in[4];
  const float* w3 = (const float*)d_in[5];
  const float* b3 = (const float*)d_in[6];
  const float* cw1 = (const float*)d_in[23];
  const float* cb1 = (const float*)d_in[24];
  const float* cw2 = (const float*)d_in[25];
  const float* cb2 = (const float*)d_in[26];
  const float* cw3 = (const float*)d_in[27];
  const float* cb3 = (const float*)d_in[28];

  float* ws = (float*)d_ws;
  float* a1    = ws;
  float* wt    = ws;
  float* comb0 = ws + 3670016;
  float* comb1 = ws + 4087808;
  float* c0    = ws + 4644864;
  float* a2    = ws + 8388608;
  float* w2t   = ws + 12582912;
  float* w3t   = ws + 12587520;
  const int C0 = 768 * 32, C1 = 1024 * 32;

  k_prep_w<<<288, 256, 0, stream>>>(w2, w2t, w3, w3t);
  k_conv1<<<32768, 256, 0, stream>>>(x, w1, b1, a1);
  k_conv2<<<dim3(512, 2), 256, 0, stream>>>(a1, w2t, b2, a2);
  // a1 now dead; everything below may write region0

  hipMemsetAsync(comb0 + 256 * 32, 0, (size_t)512 * 32 * 4, stream);
  hipMemsetAsync(comb1 + 512 * 32, 0, (size_t)512 * 32 * 4, stream);
  hipMemsetAsync(c0, 0, (size_t)2 * 512 * 32 * 4, stream);  // fallback c0,c1

  k_conv3<<<dim3(512, 2), 512, 0, stream>>>(a2, w3t, b3, comb0);

  TPtrs tp;
  for (int g = 0; g < 4; ++g) {
    tp.in[g]      = (const float*)d_in[7 + 2 * g];
    tp.out[g]     = wt + g * (512 * 768);
    tp.in[4 + g]  = (const float*)d_in[15 + 2 * g];
    tp.out[4 + g] = wt + 4 * (512 * 768) + g * (512 * 1024);
  }
  k_transpose<<<dim3(32, 16, 8), dim3(32, 8), 0, stream>>>(tp);

  float* l1base = wt + 1572864;
  const float* wl0[4] = {wt, wt + 393216, wt + 786432, wt + 1179648};
  const float* wl1[4] = {l1base, l1base + 524288, l1base + 1048576,
                         l1base + 1572864};

  CoopArgs ca;
  ca.comb0 = comb0; ca.comb1 = comb1;
  ca.w00 = wl0[0]; ca.w01 = wl0[1]; ca.w02 = wl0[2]; ca.w03 = wl0[3];
  ca.w10 = wl1[0]; ca.w11 = wl1[1]; ca.w12 = wl1[2]; ca.w13 = wl1[3];
  ca.b00 = (const float*)d_in[8];  ca.b01 = (const float*)d_in[10];
  ca.b02 = (const float*)d_in[12]; ca.b03 = (const float*)d_in[14];
  ca.b10 = (const float*)d_in[16]; ca.b11 = (const float*)d_in[18];
  ca.b12 = (const float*)d_in[20]; ca.b13 = (const float*)d_in[22];
  void* kargs[] = {&ca};
  hipError_t cerr = hipLaunchCooperativeKernel(
      (void*)k_lstm_coop, dim3(256), dim3(512), kargs, COOP_LDS_BYTES, stream);

  if (cerr != hipSuccess) {
    // fallback: proven 17-dispatch pipeline (round 5/6)
    auto L0 = [&](int t) {
      LstmArgs a;
      a.comb = comb0 + (size_t)t * C0;
      a.houtA = comb0 + (size_t)(t + 1) * C0 + 256 * 32;
      a.houtB = comb1 + (size_t)t * C1;
      a.cT = c0;
      a.Wf = wl0[0]; a.Wi = wl0[1]; a.Wg = wl0[2]; a.Wo = wl0[3];
      a.bf = (const float*)d_in[8];  a.bi = (const float*)d_in[10];
      a.bg = (const float*)d_in[12]; a.bo = (const float*)d_in[14];
      return a;
    };
    auto L1 = [&](int t) {
      LstmArgs a;
      a.comb = comb1 + (size_t)t * C1;
      a.houtA = comb1 + (size_t)(t + 1) * C1 + 512 * 32;
      a.houtB = a.houtA;
      a.cT = c0 + 16384;
      a.Wf = wl1[0]; a.Wi = wl1[1]; a.Wg = wl1[2]; a.Wo = wl1[3];
      a.bf = (const float*)d_in[16]; a.bi = (const float*)d_in[18];
      a.bg = (const float*)d_in[20]; a.bo = (const float*)d_in[22];
      return a;
    };
    k_lstm<256><<<512, 512, 0, stream>>>(L0(0));
    for (int p = 0; p < 15; ++p)
      k_lstm_pair<<<1024, 512, 0, stream>>>(L0(p + 1), L1(p));
    k_lstm<512><<<512, 512, 0, stream>>>(L1(15));
  }

  k_cls<<<32, 128, 0, stream>>>(comb1 + (size_t)16 * C1 + 512 * 32,
                                cw1, cb1, cw2, cb2, cw3, cb3, (float*)d_out);
}

// Round 9
// 687.854 us; speedup vs baseline: 2.9968x; 2.9968x over previous
//
#include <hip/hip_runtime.h>
#include <math.h>

// ---------------------------------------------------------------------------
// conv1: x[512][1][64][64] -> relu -> maxpool2 -> a1[512][16][32][32]
__global__ void k_conv1(const float* __restrict__ x, const float* __restrict__ w,
                        const float* __restrict__ bias, float* __restrict__ out) {
  int idx = blockIdx.x * 256 + threadIdx.x;
  int ox = idx & 31, oy = (idx >> 5) & 31, oc = (idx >> 10) & 15, n = idx >> 14;
  const float* im = x + n * 4096;
  float wv[9];
#pragma unroll
  for (int i = 0; i < 9; ++i) wv[i] = w[oc * 9 + i];
  float bs = bias[oc];
  float m = 0.f;
#pragma unroll
  for (int dy = 0; dy < 2; ++dy)
#pragma unroll
    for (int dx = 0; dx < 2; ++dx) {
      int cy = oy * 2 + dy, cx = ox * 2 + dx;
      float s = bs;
#pragma unroll
      for (int ky = 0; ky < 3; ++ky) {
        int yy = cy + ky - 1;
        if (yy < 0 || yy >= 64) continue;
#pragma unroll
        for (int kx = 0; kx < 3; ++kx) {
          int xx = cx + kx - 1;
          if (xx < 0 || xx >= 64) continue;
          s += im[yy * 64 + xx] * wv[ky * 3 + kx];
        }
      }
      m = fmaxf(m, fmaxf(s, 0.f));
    }
  out[idx] = m;
}

// ---------------------------------------------------------------------------
// weight prep: w2t[c][tap][32oc], w3t[c][tap][256oc]
__global__ void k_prep_w(const float* __restrict__ w2, float* __restrict__ w2t,
                         const float* __restrict__ w3, float* __restrict__ w3t) {
  int id = blockIdx.x * 256 + threadIdx.x;
  if (id < 73728) {
    int ct = id >> 8, oc = id & 255;
    int c = ct / 9, tap = ct - 9 * c;
    w3t[id] = w3[(oc * 32 + c) * 9 + tap];
  }
  if (id < 4608) {
    int ct = id >> 5, oc = id & 31;
    int c = ct / 9, tap = ct - 9 * c;
    w2t[id] = w2[(oc * 16 + c) * 9 + tap];
  }
}

// ---------------------------------------------------------------------------
// conv2: a1[512][16][32][32] -> relu -> maxpool2 -> a2[n][px=256][oc=32]
__global__ __launch_bounds__(256) void k_conv2(
    const float* __restrict__ a1, const float* __restrict__ w2t,
    const float* __restrict__ bias, float* __restrict__ a2) {
  __shared__ __align__(16) float ins[8 * 1024];
  int n = blockIdx.x, ocg = blockIdx.y;
  int tid = threadIdx.x;
  int py = tid >> 4, px = tid & 15;
  int y0 = 2 * py - 1, x0 = 2 * px - 1;
  float acc[16][4] = {};
  const float* wb = w2t + ocg * 16;
  for (int ph = 0; ph < 2; ++ph) {
    __syncthreads();
    const float4* src = (const float4*)(a1 + n * 16384 + ph * 8192);
    for (int i = tid; i < 2048; i += 256) ((float4*)ins)[i] = src[i];
    __syncthreads();
    for (int c = 0; c < 8; ++c) {
      float wv[4][4];
#pragma unroll
      for (int r = 0; r < 4; ++r) {
        int y = y0 + r;
        bool vy = (y >= 0) && (y < 32);
        int yc = vy ? y : 0;
#pragma unroll
        for (int cc = 0; cc < 4; ++cc) {
          int xx = x0 + cc;
          bool vx = (xx >= 0) && (xx < 32);
          int xc = vx ? xx : 0;
          float t = ins[c * 1024 + yc * 32 + xc];
          wv[r][cc] = (vy && vx) ? t : 0.f;
        }
      }
      int ch = ph * 8 + c;
#pragma unroll
      for (int ky = 0; ky < 3; ++ky)
#pragma unroll
        for (int kx = 0; kx < 3; ++kx) {
          const float* w16 = wb + (ch * 9 + ky * 3 + kx) * 32;
#pragma unroll
          for (int i = 0; i < 4; ++i) {
            float vv = wv[(i >> 1) + ky][(i & 1) + kx];
#pragma unroll
            for (int j = 0; j < 16; ++j) acc[j][i] += vv * w16[j];
          }
        }
    }
  }
  const float* bp = bias + ocg * 16;
  float4 o[4];
#pragma unroll
  for (int j = 0; j < 16; ++j) {
    float m = fmaxf(fmaxf(acc[j][0], acc[j][1]), fmaxf(acc[j][2], acc[j][3]));
    ((float*)o)[j] = fmaxf(m + bp[j], 0.f);
  }
  float4* dst = (float4*)(a2 + (size_t)(n * 256 + tid) * 32 + ocg * 16);
#pragma unroll
  for (int q = 0; q < 4; ++q) dst[q] = o[q];
}

// ---------------------------------------------------------------------------
// conv3 (v3, the PROVEN variant: 210us, 48 VGPR, no spill) -> comb0[t][ch][b]
// 256 threads = 4 waves x 8 oc, grid (512 n, 8 ocb). Channel-split staging
// (16ch/phase, 25.9KB LDS); weights via wave-uniform scalar loads.
__global__ __launch_bounds__(256) void k_conv3(
    const float* __restrict__ a2, const float* __restrict__ w3t,
    const float* __restrict__ bias, float* __restrict__ comb0) {
  __shared__ __align__(16) float ins[324 * 20];  // 25,920 B
  int n = blockIdx.x, ocb = blockIdx.y;
  int tid = threadIdx.x;
  for (int i = tid; i < 1620; i += 256) ((float4*)ins)[i] = float4{0.f, 0.f, 0.f, 0.f};
  int wvid = __builtin_amdgcn_readfirstlane(tid >> 6);
  int lane = tid & 63;
  int tr = lane >> 4, tc = lane & 15;
  float acc[4][8] = {};
  const float* wbase = w3t + ocb * 32 + wvid * 8;
  const float4* src = (const float4*)(a2 + (size_t)n * 8192);
  for (int hf = 0; hf < 2; ++hf) {
    __syncthreads();
    for (int i = tid; i < 1024; i += 256) {
      int px = i >> 2, cg = i & 3;
      int p = ((px >> 4) + 1) * 18 + (px & 15) + 1;
      ((float4*)ins)[p * 5 + cg] = src[px * 8 + hf * 4 + cg];
    }
    __syncthreads();
    for (int cg = 0; cg < 4; ++cg) {
      float4 v[6][3];
#pragma unroll
      for (int dr = 0; dr < 6; ++dr)
#pragma unroll
        for (int dc = 0; dc < 3; ++dc)
          v[dr][dc] = ((const float4*)ins)[((4 * tr + dr) * 18 + tc + dc) * 5 + cg];
#pragma unroll
      for (int ky = 0; ky < 3; ++ky)
#pragma unroll
        for (int kx = 0; kx < 3; ++kx)
#pragma unroll
          for (int c = 0; c < 4; ++c) {
            const float* w8 = wbase + (((hf * 4 + cg) * 4 + c) * 9 + ky * 3 + kx) * 256;
#pragma unroll
            for (int i = 0; i < 4; ++i) {
              float vv = ((const float*)&v[i + ky][kx])[c];
#pragma unroll
              for (int j = 0; j < 8; ++j) acc[i][j] += vv * w8[j];
            }
          }
    }
  }
  const float* bp = bias + ocb * 32 + wvid * 8;
  int bb = n >> 4, tt = n & 15;
#pragma unroll
  for (int j = 0; j < 8; ++j) {
    float bj = bp[j];
    float s = 0.f;
#pragma unroll
    for (int i = 0; i < 4; ++i) s += fmaxf(acc[i][j] + bj, 0.f);
#pragma unroll
    for (int off = 32; off; off >>= 1) s += __shfl_down(s, off, 64);
    if (lane == 0) {
      int oc = ocb * 32 + wvid * 8 + j;
      comb0[(size_t)(tt * 768 + oc) * 32 + bb] = s * (1.f / 256.f);
    }
  }
}

// ---------------------------------------------------------------------------
// pack: p[h][k][4] = (Wf[k][h], Wi[k][h], Wg[k][h], Wo[k][h]) from original
// W[fan][512] arrays. Coalesced loads, LDS transpose, coalesced float4 stores.
__global__ void k_pack(const float* __restrict__ Wf, const float* __restrict__ Wi,
                       const float* __restrict__ Wg, const float* __restrict__ Wo,
                       float* __restrict__ p, int fan) {
  __shared__ float t[4][32][33];
  int k0 = blockIdx.x * 32, h0 = blockIdx.y * 32;
  int tx = threadIdx.x & 31, ty = threadIdx.x >> 5;  // 32 x 8
  const float* Ws[4] = {Wf, Wi, Wg, Wo};
#pragma unroll
  for (int g = 0; g < 4; ++g)
    for (int r = 0; r < 32; r += 8)
      t[g][ty + r][tx] = Ws[g][(size_t)(k0 + ty + r) * 512 + h0 + tx];
  __syncthreads();
  for (int r = 0; r < 32; r += 8) {
    int hh = ty + r;
    float4 v = {t[0][tx][hh], t[1][tx][hh], t[2][tx][hh], t[3][tx][hh]};
    ((float4*)p)[(size_t)(h0 + hh) * fan + k0 + tx] = v;
  }
}

// ---------------------------------------------------------------------------
// LSTM scalar-weight step: block = 1 h, 8 waves = 8 k-chunks, lane = (ks, b).
// Weights p[h][k][4gates] via wave-uniform SGPR loads (free); acts via one
// fully-coalesced 256B wave load per 2k (dup=1, vs 4x in the old mapping).
// Per 2k per lane: 4 cndmask + 4 FMA.
struct SArgs {
  const float* comb;   // [FAN][32]
  const float* pw;     // [512][FAN][4]
  float* houtA; float* houtB; float* cT;
  const float* bf; const float* bi; const float* bg; const float* bo;
};

template <int FAN>
__device__ __forceinline__ void lstm_sbody(int h, int tid, const SArgs& A,
                                           float* __restrict__ gsum) {
  constexpr int CH = FAN / 8;
  const int wv = __builtin_amdgcn_readfirstlane(tid >> 6);
  const int lane = tid & 63;
  const int ks = lane >> 5, b = lane & 31;
  const int kb = wv * CH;
  const float4* pw4 = (const float4*)A.pw + (size_t)h * FAN + kb;
  const float* ac = A.comb + (size_t)kb * 32 + lane;
  float a0 = 0.f, a1 = 0.f, a2 = 0.f, a3 = 0.f;
#pragma unroll 8
  for (int kk = 0; kk < CH; kk += 2) {
    float4 w0 = pw4[kk];
    float4 w1 = pw4[kk + 1];
    float av = ac[kk * 32];
    a0 += av * (ks ? w1.x : w0.x);
    a1 += av * (ks ? w1.y : w0.y);
    a2 += av * (ks ? w1.z : w0.z);
    a3 += av * (ks ? w1.w : w0.w);
  }
  a0 += __shfl_xor(a0, 32);
  a1 += __shfl_xor(a1, 32);
  a2 += __shfl_xor(a2, 32);
  a3 += __shfl_xor(a3, 32);
  if (lane < 32) {
    gsum[(wv * 4 + 0) * 33 + b] = a0;
    gsum[(wv * 4 + 1) * 33 + b] = a1;
    gsum[(wv * 4 + 2) * 33 + b] = a2;
    gsum[(wv * 4 + 3) * 33 + b] = a3;
  }
  __syncthreads();
  if (tid < 32) {
    float fp = A.bf[h], ip = A.bi[h], gp = A.bg[h], op = A.bo[h];
#pragma unroll
    for (int q = 0; q < 8; ++q) {
      fp += gsum[(q * 4 + 0) * 33 + tid];
      ip += gsum[(q * 4 + 1) * 33 + tid];
      gp += gsum[(q * 4 + 2) * 33 + tid];
      op += gsum[(q * 4 + 3) * 33 + tid];
    }
    float ft = 1.f / (1.f + expf(-fp));
    float it_ = 1.f / (1.f + expf(-ip));
    float gt = tanhf(gp);
    float ot = 1.f / (1.f + expf(-op));
    float cn = ft * A.cT[h * 32 + tid] + it_ * gt;
    A.cT[h * 32 + tid] = cn;
    float hn = ot * tanhf(cn);
    A.houtA[h * 32 + tid] = hn;
    A.houtB[h * 32 + tid] = hn;
  }
}

__global__ __launch_bounds__(512) void k_lstm_s0(SArgs a) {
  __shared__ float gsum[32 * 33];
  lstm_sbody<768>(blockIdx.x, threadIdx.x, a, gsum);
}
__global__ __launch_bounds__(512) void k_lstm_s1(SArgs a) {
  __shared__ float gsum[32 * 33];
  lstm_sbody<1024>(blockIdx.x, threadIdx.x, a, gsum);
}
// pipeline pair: blocks 0..511 = layer0 @ t+1, 512..1023 = layer1 @ t
// (independent by dataflow; both inputs written by the previous dispatch).
__global__ __launch_bounds__(512) void k_lstm_spair(SArgs a0, SArgs a1) {
  __shared__ float gsum[32 * 33];
  if (blockIdx.x < 512)
    lstm_sbody<768>(blockIdx.x, threadIdx.x, a0, gsum);
  else
    lstm_sbody<1024>(blockIdx.x - 512, threadIdx.x, a1, gsum);
}

// ---------------------------------------------------------------------------
// classifier: input h1T layout [h][b] (a comb slice)
__global__ void k_cls(const float* __restrict__ h1T, const float* __restrict__ cw1,
                      const float* __restrict__ cb1, const float* __restrict__ cw2,
                      const float* __restrict__ cb2, const float* __restrict__ cw3,
                      const float* __restrict__ cb3, float* __restrict__ out) {
  __shared__ float hv[512];
  __shared__ float y1[128];
  __shared__ float y2[64];
  int b = blockIdx.x, tid = threadIdx.x;
  for (int i = tid; i < 512; i += 128) hv[i] = h1T[i * 32 + b];
  __syncthreads();
  float s = cb1[tid];
  for (int k = 0; k < 512; ++k) s += hv[k] * cw1[k * 128 + tid];
  y1[tid] = fmaxf(s, 0.f);
  __syncthreads();
  if (tid < 64) {
    float s2 = cb2[tid];
    for (int k = 0; k < 128; ++k) s2 += y1[k] * cw2[k * 64 + tid];
    y2[tid] = fmaxf(s2, 0.f);
  }
  __syncthreads();
  if (tid < 6) {
    float s3 = cb3[tid];
    for (int k = 0; k < 64; ++k) s3 += y2[k] * cw3[k * 6 + tid];
    out[b * 6 + tid] = s3;
  }
}

// ---------------------------------------------------------------------------
// Workspace (floats):
//  region0 [0..8,388,608) = a1 (conv1 out, dead after conv2); then reused:
//    p0    @ 0          [1,572,864]  packed l0 weights [512][768][4]
//    p1    @ 1,572,864  [2,097,152]  packed l1 weights [512][1024][4]
//    comb0 @ 3,670,016  [17*768*32  = 417,792]  comb0[t] = [emb(t), h0(t-1)]
//    comb1 @ 4,087,808  [17*1024*32 = 557,056]  comb1[t] = [h0(t), h1(t-1)]
//    c0,c1 @ 4,644,864  [2*16,384]
//  a2  @ 8,388,608  [4,194,304]   layout [n][px][oc]
//  w2t @ 12,582,912 [4,608];  w3t @ 12,587,520 [73,728]
extern "C" void kernel_launch(void* const* d_in, const int* in_sizes, int n_in,
                              void* d_out, int out_size, void* d_ws, size_t ws_size,
                              hipStream_t stream) {
  const float* x  = (const float*)d_in[0];
  const float* w1 = (const float*)d_in[1];
  const float* b1 = (const float*)d_in[2];
  const float* w2 = (const float*)d_in[3];
  const float* b2 = (const float*)d_in[4];
  const float* w3 = (const float*)d_in[5];
  const float* b3 = (const float*)d_in[6];
  const float* cw1 = (const float*)d_in[23];
  const float* cb1 = (const float*)d_in[24];
  const float* cw2 = (const float*)d_in[25];
  const float* cb2 = (const float*)d_in[26];
  const float* cw3 = (const float*)d_in[27];
  const float* cb3 = (const float*)d_in[28];

  float* ws = (float*)d_ws;
  float* a1    = ws;
  float* p0    = ws;
  float* p1    = ws + 1572864;
  float* comb0 = ws + 3670016;
  float* comb1 = ws + 4087808;
  float* c0    = ws + 4644864;
  float* c1    = ws + 4661248;
  float* a2    = ws + 8388608;
  float* w2t   = ws + 12582912;
  float* w3t   = ws + 12587520;
  const int C0 = 768 * 32, C1 = 1024 * 32;

  k_prep_w<<<288, 256, 0, stream>>>(w2, w2t, w3, w3t);
  k_conv1<<<32768, 256, 0, stream>>>(x, w1, b1, a1);
  k_conv2<<<dim3(512, 2), 256, 0, stream>>>(a1, w2t, b2, a2);
  // a1 now dead; everything below may write region0

  hipMemsetAsync(comb0 + 256 * 32, 0, (size_t)512 * 32 * 4, stream);
  hipMemsetAsync(comb1 + 512 * 32, 0, (size_t)512 * 32 * 4, stream);
  hipMemsetAsync(c0, 0, (size_t)2 * 512 * 32 * 4, stream);

  k_conv3<<<dim3(512, 8), 256, 0, stream>>>(a2, w3t, b3, comb0);

  // pack LSTM weights [h][k][4g] straight from the original W[fan][512] arrays
  k_pack<<<dim3(24, 16), 256, 0, stream>>>(
      (const float*)d_in[7], (const float*)d_in[9],
      (const float*)d_in[11], (const float*)d_in[13], p0, 768);
  k_pack<<<dim3(32, 16), 256, 0, stream>>>(
      (const float*)d_in[15], (const float*)d_in[17],
      (const float*)d_in[19], (const float*)d_in[21], p1, 1024);

  auto L0 = [&](int t) {
    SArgs a;
    a.comb = comb0 + (size_t)t * C0;
    a.pw = p0;
    a.houtA = comb0 + (size_t)(t + 1) * C0 + 256 * 32;
    a.houtB = comb1 + (size_t)t * C1;
    a.cT = c0;
    a.bf = (const float*)d_in[8];  a.bi = (const float*)d_in[10];
    a.bg = (const float*)d_in[12]; a.bo = (const float*)d_in[14];
    return a;
  };
  auto L1 = [&](int t) {
    SArgs a;
    a.comb = comb1 + (size_t)t * C1;
    a.pw = p1;
    a.houtA = comb1 + (size_t)(t + 1) * C1 + 512 * 32;
    a.houtB = a.houtA;
    a.cT = c1;
    a.bf = (const float*)d_in[16]; a.bi = (const float*)d_in[18];
    a.bg = (const float*)d_in[20]; a.bo = (const float*)d_in[22];
    return a;
  };

  k_lstm_s0<<<512, 512, 0, stream>>>(L0(0));
  for (int p = 0; p < 15; ++p)
    k_lstm_spair<<<1024, 512, 0, stream>>>(L0(p + 1), L1(p));
  k_lstm_s1<<<512, 512, 0, stream>>>(L1(15));

  k_cls<<<32, 128, 0, stream>>>(comb1 + (size_t)16 * C1 + 512 * 32,
                                cw1, cb1, cw2, cb2, cw3, cb3, (float*)d_out);
}

// Round 10
// 617.373 us; speedup vs baseline: 3.3389x; 1.1142x over previous
//
#include <hip/hip_runtime.h>
#include <math.h>

// ---------------------------------------------------------------------------
// conv1: x[512][1][64][64] -> relu -> maxpool2 -> a1[512][16][32][32]
__global__ void k_conv1(const float* __restrict__ x, const float* __restrict__ w,
                        const float* __restrict__ bias, float* __restrict__ out) {
  int idx = blockIdx.x * 256 + threadIdx.x;
  int ox = idx & 31, oy = (idx >> 5) & 31, oc = (idx >> 10) & 15, n = idx >> 14;
  const float* im = x + n * 4096;
  float wv[9];
#pragma unroll
  for (int i = 0; i < 9; ++i) wv[i] = w[oc * 9 + i];
  float bs = bias[oc];
  float m = 0.f;
#pragma unroll
  for (int dy = 0; dy < 2; ++dy)
#pragma unroll
    for (int dx = 0; dx < 2; ++dx) {
      int cy = oy * 2 + dy, cx = ox * 2 + dx;
      float s = bs;
#pragma unroll
      for (int ky = 0; ky < 3; ++ky) {
        int yy = cy + ky - 1;
        if (yy < 0 || yy >= 64) continue;
#pragma unroll
        for (int kx = 0; kx < 3; ++kx) {
          int xx = cx + kx - 1;
          if (xx < 0 || xx >= 64) continue;
          s += im[yy * 64 + xx] * wv[ky * 3 + kx];
        }
      }
      m = fmaxf(m, fmaxf(s, 0.f));
    }
  out[idx] = m;
}

// ---------------------------------------------------------------------------
// weight prep: w2t[c][tap][32oc], w3t[c][tap][256oc]
__global__ void k_prep_w(const float* __restrict__ w2, float* __restrict__ w2t,
                         const float* __restrict__ w3, float* __restrict__ w3t) {
  int id = blockIdx.x * 256 + threadIdx.x;
  if (id < 73728) {
    int ct = id >> 8, oc = id & 255;
    int c = ct / 9, tap = ct - 9 * c;
    w3t[id] = w3[(oc * 32 + c) * 9 + tap];
  }
  if (id < 4608) {
    int ct = id >> 5, oc = id & 31;
    int c = ct / 9, tap = ct - 9 * c;
    w2t[id] = w2[(oc * 16 + c) * 9 + tap];
  }
}

// ---------------------------------------------------------------------------
// conv2: a1[512][16][32][32] -> relu -> maxpool2 -> a2[n][px=256][oc=32]
__global__ __launch_bounds__(256) void k_conv2(
    const float* __restrict__ a1, const float* __restrict__ w2t,
    const float* __restrict__ bias, float* __restrict__ a2) {
  __shared__ __align__(16) float ins[8 * 1024];
  int n = blockIdx.x, ocg = blockIdx.y;
  int tid = threadIdx.x;
  int py = tid >> 4, px = tid & 15;
  int y0 = 2 * py - 1, x0 = 2 * px - 1;
  float acc[16][4] = {};
  const float* wb = w2t + ocg * 16;
  for (int ph = 0; ph < 2; ++ph) {
    __syncthreads();
    const float4* src = (const float4*)(a1 + n * 16384 + ph * 8192);
    for (int i = tid; i < 2048; i += 256) ((float4*)ins)[i] = src[i];
    __syncthreads();
    for (int c = 0; c < 8; ++c) {
      float wv[4][4];
#pragma unroll
      for (int r = 0; r < 4; ++r) {
        int y = y0 + r;
        bool vy = (y >= 0) && (y < 32);
        int yc = vy ? y : 0;
#pragma unroll
        for (int cc = 0; cc < 4; ++cc) {
          int xx = x0 + cc;
          bool vx = (xx >= 0) && (xx < 32);
          int xc = vx ? xx : 0;
          float t = ins[c * 1024 + yc * 32 + xc];
          wv[r][cc] = (vy && vx) ? t : 0.f;
        }
      }
      int ch = ph * 8 + c;
#pragma unroll
      for (int ky = 0; ky < 3; ++ky)
#pragma unroll
        for (int kx = 0; kx < 3; ++kx) {
          const float* w16 = wb + (ch * 9 + ky * 3 + kx) * 32;
#pragma unroll
          for (int i = 0; i < 4; ++i) {
            float vv = wv[(i >> 1) + ky][(i & 1) + kx];
#pragma unroll
            for (int j = 0; j < 16; ++j) acc[j][i] += vv * w16[j];
          }
        }
    }
  }
  const float* bp = bias + ocg * 16;
  float4 o[4];
#pragma unroll
  for (int j = 0; j < 16; ++j) {
    float m = fmaxf(fmaxf(acc[j][0], acc[j][1]), fmaxf(acc[j][2], acc[j][3]));
    ((float*)o)[j] = fmaxf(m + bp[j], 0.f);
  }
  float4* dst = (float4*)(a2 + (size_t)(n * 256 + tid) * 32 + ocg * 16);
#pragma unroll
  for (int q = 0; q < 4; ++q) dst[q] = o[q];
}

// ---------------------------------------------------------------------------
// conv3 (proven v3: 210us, 48 VGPR, no spill) -> comb0[t][ch][b]
__global__ __launch_bounds__(256) void k_conv3(
    const float* __restrict__ a2, const float* __restrict__ w3t,
    const float* __restrict__ bias, float* __restrict__ comb0) {
  __shared__ __align__(16) float ins[324 * 20];  // 25,920 B
  int n = blockIdx.x, ocb = blockIdx.y;
  int tid = threadIdx.x;
  for (int i = tid; i < 1620; i += 256) ((float4*)ins)[i] = float4{0.f, 0.f, 0.f, 0.f};
  int wvid = __builtin_amdgcn_readfirstlane(tid >> 6);
  int lane = tid & 63;
  int tr = lane >> 4, tc = lane & 15;
  float acc[4][8] = {};
  const float* wbase = w3t + ocb * 32 + wvid * 8;
  const float4* src = (const float4*)(a2 + (size_t)n * 8192);
  for (int hf = 0; hf < 2; ++hf) {
    __syncthreads();
    for (int i = tid; i < 1024; i += 256) {
      int px = i >> 2, cg = i & 3;
      int p = ((px >> 4) + 1) * 18 + (px & 15) + 1;
      ((float4*)ins)[p * 5 + cg] = src[px * 8 + hf * 4 + cg];
    }
    __syncthreads();
    for (int cg = 0; cg < 4; ++cg) {
      float4 v[6][3];
#pragma unroll
      for (int dr = 0; dr < 6; ++dr)
#pragma unroll
        for (int dc = 0; dc < 3; ++dc)
          v[dr][dc] = ((const float4*)ins)[((4 * tr + dr) * 18 + tc + dc) * 5 + cg];
#pragma unroll
      for (int ky = 0; ky < 3; ++ky)
#pragma unroll
        for (int kx = 0; kx < 3; ++kx)
#pragma unroll
          for (int c = 0; c < 4; ++c) {
            const float* w8 = wbase + (((hf * 4 + cg) * 4 + c) * 9 + ky * 3 + kx) * 256;
#pragma unroll
            for (int i = 0; i < 4; ++i) {
              float vv = ((const float*)&v[i + ky][kx])[c];
#pragma unroll
              for (int j = 0; j < 8; ++j) acc[i][j] += vv * w8[j];
            }
          }
    }
  }
  const float* bp = bias + ocb * 32 + wvid * 8;
  int bb = n >> 4, tt = n & 15;
#pragma unroll
  for (int j = 0; j < 8; ++j) {
    float bj = bp[j];
    float s = 0.f;
#pragma unroll
    for (int i = 0; i < 4; ++i) s += fmaxf(acc[i][j] + bj, 0.f);
#pragma unroll
    for (int off = 32; off; off >>= 1) s += __shfl_down(s, off, 64);
    if (lane == 0) {
      int oc = ocb * 32 + wvid * 8 + j;
      comb0[(size_t)(tt * 768 + oc) * 32 + bb] = s * (1.f / 256.f);
    }
  }
}

// ---------------------------------------------------------------------------
// pack: p[h][k][4] = (Wf[k][h], Wi[k][h], Wg[k][h], Wo[k][h])
__global__ void k_pack(const float* __restrict__ Wf, const float* __restrict__ Wi,
                       const float* __restrict__ Wg, const float* __restrict__ Wo,
                       float* __restrict__ p, int fan) {
  __shared__ float t[4][32][33];
  int k0 = blockIdx.x * 32, h0 = blockIdx.y * 32;
  int tx = threadIdx.x & 31, ty = threadIdx.x >> 5;  // 32 x 8
  const float* Ws[4] = {Wf, Wi, Wg, Wo};
#pragma unroll
  for (int g = 0; g < 4; ++g)
    for (int r = 0; r < 32; r += 8)
      t[g][ty + r][tx] = Ws[g][(size_t)(k0 + ty + r) * 512 + h0 + tx];
  __syncthreads();
  for (int r = 0; r < 32; r += 8) {
    int hh = ty + r;
    float4 v = {t[0][tx][hh], t[1][tx][hh], t[2][tx][hh], t[3][tx][hh]};
    ((float4*)p)[(size_t)(h0 + hh) * fan + k0 + tx] = v;
  }
}

// ---------------------------------------------------------------------------
// Persistent cooperative LSTM with CUSTOM barrier (grid.sync measured at
// ~77us/iter in round 8 -- never call it). 256 blocks x 512 threads, coop
// launch ONLY for the residency guarantee. Block = 2 h; weights staged in
// LDS once; c/biases in registers; h published via write-through agent-scope
// stores; barrier = monotonic counter (release add, relaxed spin, one
// acquire fence on exit).
struct Coop2Args {
  float* comb0; float* comb1;
  const float* p0; const float* p1;   // packed [512][FAN][4]
  const float* b00; const float* b01; const float* b02; const float* b03;
  const float* b10; const float* b11; const float* b12; const float* b13;
  int* bar;
};

// dynamic LDS (floats): wl0 [0,6144) | wl1 [6144,14336) | gsum [14336,22784)
// | pre [22784,23040)  => 92,160 B (<160KB -> 1 block/CU always fits)
#define COOP2_LDS_BYTES (23040 * 4)

template <int FAN>
__device__ __forceinline__ void coop_step(
    int hbase, int tid, const float* __restrict__ comb,
    const float* __restrict__ wl,
    float* __restrict__ houtA, float* __restrict__ houtB,
    float bfv, float biv, float bgv, float bov,
    float& creg, float* __restrict__ gsum, float* __restrict__ pre) {
  constexpr int CH = FAN / 32;       // k per thread (24 or 32)
  const int hs = tid >> 8, kc = (tid >> 3) & 31, bq = tid & 7;
  const float4* w4 = (const float4*)wl + (size_t)hs * FAN + kc * CH;
  const float4* a4 = (const float4*)comb;
  const int rot = kc & 7;            // breaks CH%8==0 LDS bank collapse
  float4 af{0,0,0,0}, ai{0,0,0,0}, ag{0,0,0,0}, ao{0,0,0,0};
#pragma unroll
  for (int kk = 0; kk < CH; ++kk) {
    int idx = kk + rot; if (idx >= CH) idx -= CH;
    float4 w = w4[idx];                                 // 4 gates of one k
    float4 a = a4[(size_t)(kc * CH + idx) * 8 + bq];    // 4 batches of one k
    af.x += w.x*a.x; af.y += w.x*a.y; af.z += w.x*a.z; af.w += w.x*a.w;
    ai.x += w.y*a.x; ai.y += w.y*a.y; ai.z += w.y*a.z; ai.w += w.y*a.w;
    ag.x += w.z*a.x; ag.y += w.z*a.y; ag.z += w.z*a.z; ag.w += w.z*a.w;
    ao.x += w.w*a.x; ao.y += w.w*a.y; ao.z += w.w*a.z; ao.w += w.w*a.w;
  }
  __syncthreads();   // previous consumer of gsum/pre is done
  {
    const float* accs[4] = {(const float*)&af, (const float*)&ai,
                            (const float*)&ag, (const float*)&ao};
#pragma unroll
    for (int g = 0; g < 4; ++g)
#pragma unroll
      for (int j = 0; j < 4; ++j)
        gsum[((hs * 4 + g) * 32 + 4 * bq + j) * 33 + kc] = accs[g][j];
  }
  __syncthreads();
  if (tid < 256) {
    int hs2 = tid >> 7, g = (tid >> 5) & 3, b = tid & 31;
    int base = ((hs2 * 4 + g) * 32 + b) * 33;
    float s = 0.f;
#pragma unroll
    for (int q = 0; q < 32; ++q) s += gsum[base + q];
    pre[(hs2 * 4 + g) * 32 + b] = s;
  }
  __syncthreads();
  if (tid < 64) {
    int hs2 = tid >> 5, b = tid & 31;
    float fp = pre[(hs2 * 4 + 0) * 32 + b] + bfv;
    float ip = pre[(hs2 * 4 + 1) * 32 + b] + biv;
    float gp = pre[(hs2 * 4 + 2) * 32 + b] + bgv;
    float op = pre[(hs2 * 4 + 3) * 32 + b] + bov;
    float ft = 1.f / (1.f + expf(-fp));
    float it_ = 1.f / (1.f + expf(-ip));
    float gt = tanhf(gp);
    float ot = 1.f / (1.f + expf(-op));
    float cn = ft * creg + it_ * gt;
    creg = cn;
    float hn = ot * tanhf(cn);
    int hh = hbase + hs2;
    __hip_atomic_store(&houtA[hh * 32 + b], hn, __ATOMIC_RELAXED,
                       __HIP_MEMORY_SCOPE_AGENT);
    if (houtB != houtA)
      __hip_atomic_store(&houtB[hh * 32 + b], hn, __ATOMIC_RELAXED,
                         __HIP_MEMORY_SCOPE_AGENT);
  }
}

__global__ __launch_bounds__(512) void k_lstm_coop2(Coop2Args A) {
  extern __shared__ float smem[];
  float* wl0 = smem;
  float* wl1 = smem + 6144;
  float* gsum = smem + 14336;
  float* pre = smem + 22784;
  const int tid = threadIdx.x;
  const int hbase = blockIdx.x * 2;
  for (int i = tid; i < 1536; i += 512) {
    int hs = i / 768, k = i - hs * 768;
    ((float4*)wl0)[hs * 768 + k] =
        ((const float4*)A.p0)[(size_t)(hbase + hs) * 768 + k];
  }
  for (int i = tid; i < 2048; i += 512) {
    int hs = i >> 10, k = i & 1023;
    ((float4*)wl1)[hs * 1024 + k] =
        ((const float4*)A.p1)[(size_t)(hbase + hs) * 1024 + k];
  }
  float bf0 = 0, bi0 = 0, bg0 = 0, bo0 = 0;
  float bf1 = 0, bi1 = 0, bg1 = 0, bo1 = 0;
  if (tid < 64) {
    int hh = hbase + (tid >> 5);
    bf0 = A.b00[hh]; bi0 = A.b01[hh]; bg0 = A.b02[hh]; bo0 = A.b03[hh];
    bf1 = A.b10[hh]; bi1 = A.b11[hh]; bg1 = A.b12[hh]; bo1 = A.b13[hh];
  }
  __syncthreads();
  float c0reg = 0.f, c1reg = 0.f;
  const int C0 = 768 * 32, C1 = 1024 * 32;
  for (int it = 0; it <= 16; ++it) {
    if (it < 16)
      coop_step<768>(hbase, tid, A.comb0 + (size_t)it * C0, wl0,
                     A.comb0 + (size_t)(it + 1) * C0 + 256 * 32,
                     A.comb1 + (size_t)it * C1,
                     bf0, bi0, bg0, bo0, c0reg, gsum, pre);
    if (it >= 1)
      coop_step<1024>(hbase, tid, A.comb1 + (size_t)(it - 1) * C1, wl1,
                      A.comb1 + (size_t)it * C1 + 512 * 32,
                      A.comb1 + (size_t)it * C1 + 512 * 32,
                      bf1, bi1, bg1, bo1, c1reg, gsum, pre);
    if (it < 16) {
      __syncthreads();
      if (tid == 0) {
        __hip_atomic_fetch_add(A.bar, 1, __ATOMIC_RELEASE,
                               __HIP_MEMORY_SCOPE_AGENT);
        const int target = 256 * (it + 1);
        while (__hip_atomic_load(A.bar, __ATOMIC_RELAXED,
                                 __HIP_MEMORY_SCOPE_AGENT) < target)
          __builtin_amdgcn_s_sleep(8);
        __builtin_amdgcn_fence(__ATOMIC_ACQUIRE, "agent");
      }
      __syncthreads();
    }
  }
}

// ---------------------------------------------------------------------------
// Fallback LSTM (round-9 proven): used only if coop launch is rejected.
struct SArgs {
  const float* comb; const float* pw;
  float* houtA; float* houtB; float* cT;
  const float* bf; const float* bi; const float* bg; const float* bo;
};

template <int FAN>
__device__ __forceinline__ void lstm_sbody(int h, int tid, const SArgs& A,
                                           float* __restrict__ gsum) {
  constexpr int CH = FAN / 8;
  const int wv = __builtin_amdgcn_readfirstlane(tid >> 6);
  const int lane = tid & 63;
  const int ks = lane >> 5, b = lane & 31;
  const int kb = wv * CH;
  const float4* pw4 = (const float4*)A.pw + (size_t)h * FAN + kb;
  const float* ac = A.comb + (size_t)kb * 32 + lane;
  float a0 = 0.f, a1 = 0.f, a2 = 0.f, a3 = 0.f;
#pragma unroll 8
  for (int kk = 0; kk < CH; kk += 2) {
    float4 w0 = pw4[kk];
    float4 w1 = pw4[kk + 1];
    float av = ac[kk * 32];
    a0 += av * (ks ? w1.x : w0.x);
    a1 += av * (ks ? w1.y : w0.y);
    a2 += av * (ks ? w1.z : w0.z);
    a3 += av * (ks ? w1.w : w0.w);
  }
  a0 += __shfl_xor(a0, 32);
  a1 += __shfl_xor(a1, 32);
  a2 += __shfl_xor(a2, 32);
  a3 += __shfl_xor(a3, 32);
  if (lane < 32) {
    gsum[(wv * 4 + 0) * 33 + b] = a0;
    gsum[(wv * 4 + 1) * 33 + b] = a1;
    gsum[(wv * 4 + 2) * 33 + b] = a2;
    gsum[(wv * 4 + 3) * 33 + b] = a3;
  }
  __syncthreads();
  if (tid < 32) {
    float fp = A.bf[h], ip = A.bi[h], gp = A.bg[h], op = A.bo[h];
#pragma unroll
    for (int q = 0; q < 8; ++q) {
      fp += gsum[(q * 4 + 0) * 33 + tid];
      ip += gsum[(q * 4 + 1) * 33 + tid];
      gp += gsum[(q * 4 + 2) * 33 + tid];
      op += gsum[(q * 4 + 3) * 33 + tid];
    }
    float ft = 1.f / (1.f + expf(-fp));
    float it_ = 1.f / (1.f + expf(-ip));
    float gt = tanhf(gp);
    float ot = 1.f / (1.f + expf(-op));
    float cn = ft * A.cT[h * 32 + tid] + it_ * gt;
    A.cT[h * 32 + tid] = cn;
    float hn = ot * tanhf(cn);
    A.houtA[h * 32 + tid] = hn;
    A.houtB[h * 32 + tid] = hn;
  }
}

__global__ __launch_bounds__(512) void k_lstm_s0(SArgs a) {
  __shared__ float gsum[32 * 33];
  lstm_sbody<768>(blockIdx.x, threadIdx.x, a, gsum);
}
__global__ __launch_bounds__(512) void k_lstm_s1(SArgs a) {
  __shared__ float gsum[32 * 33];
  lstm_sbody<1024>(blockIdx.x, threadIdx.x, a, gsum);
}
__global__ __launch_bounds__(512) void k_lstm_spair(SArgs a0, SArgs a1) {
  __shared__ float gsum[32 * 33];
  if (blockIdx.x < 512)
    lstm_sbody<768>(blockIdx.x, threadIdx.x, a0, gsum);
  else
    lstm_sbody<1024>(blockIdx.x - 512, threadIdx.x, a1, gsum);
}

// ---------------------------------------------------------------------------
// classifier: input h1T layout [h][b] (a comb slice)
__global__ void k_cls(const float* __restrict__ h1T, const float* __restrict__ cw1,
                      const float* __restrict__ cb1, const float* __restrict__ cw2,
                      const float* __restrict__ cb2, const float* __restrict__ cw3,
                      const float* __restrict__ cb3, float* __restrict__ out) {
  __shared__ float hv[512];
  __shared__ float y1[128];
  __shared__ float y2[64];
  int b = blockIdx.x, tid = threadIdx.x;
  for (int i = tid; i < 512; i += 128) hv[i] = h1T[i * 32 + b];
  __syncthreads();
  float s = cb1[tid];
  for (int k = 0; k < 512; ++k) s += hv[k] * cw1[k * 128 + tid];
  y1[tid] = fmaxf(s, 0.f);
  __syncthreads();
  if (tid < 64) {
    float s2 = cb2[tid];
    for (int k = 0; k < 128; ++k) s2 += y1[k] * cw2[k * 64 + tid];
    y2[tid] = fmaxf(s2, 0.f);
  }
  __syncthreads();
  if (tid < 6) {
    float s3 = cb3[tid];
    for (int k = 0; k < 64; ++k) s3 += y2[k] * cw3[k * 6 + tid];
    out[b * 6 + tid] = s3;
  }
}

// ---------------------------------------------------------------------------
// Workspace (floats):
//  region0 [0..8,388,608) = a1 (dead after conv2); then reused:
//    p0    @ 0          [1,572,864]  packed l0 weights [512][768][4]
//    p1    @ 1,572,864  [2,097,152]  packed l1 weights [512][1024][4]
//    comb0 @ 3,670,016  [417,792]   comb0[t] = [emb(t), h0(t-1)]
//    comb1 @ 4,087,808  [557,056]   comb1[t] = [h0(t), h1(t-1)]
//    c0,c1 @ 4,644,864  [2*16,384]  (fallback only)
//    bar   @ 4,677,632  [1 int]     coop barrier counter
//  a2  @ 8,388,608  [4,194,304];  w2t @ 12,582,912;  w3t @ 12,587,520
extern "C" void kernel_launch(void* const* d_in, const int* in_sizes, int n_in,
                              void* d_out, int out_size, void* d_ws, size_t ws_size,
                              hipStream_t stream) {
  const float* x  = (const float*)d_in[0];
  const float* w1 = (const float*)d_in[1];
  const float* b1 = (const float*)d_in[2];
  const float* w2 = (const float*)d_in[3];
  const float* b2 = (const float*)d_in[4];
  const float* w3 = (const float*)d_in[5];
  const float* b3 = (const float*)d_in[6];
  const float* cw1 = (const float*)d_in[23];
  const float* cb1 = (const float*)d_in[24];
  const float* cw2 = (const float*)d_in[25];
  const float* cb2 = (const float*)d_in[26];
  const float* cw3 = (const float*)d_in[27];
  const float* cb3 = (const float*)d_in[28];

  float* ws = (float*)d_ws;
  float* a1    = ws;
  float* p0    = ws;
  float* p1    = ws + 1572864;
  float* comb0 = ws + 3670016;
  float* comb1 = ws + 4087808;
  float* c0    = ws + 4644864;
  float* c1    = ws + 4661248;
  int*   bar   = (int*)(ws + 4677632);
  float* a2    = ws + 8388608;
  float* w2t   = ws + 12582912;
  float* w3t   = ws + 12587520;
  const int C0 = 768 * 32, C1 = 1024 * 32;

  k_prep_w<<<288, 256, 0, stream>>>(w2, w2t, w3, w3t);
  k_conv1<<<32768, 256, 0, stream>>>(x, w1, b1, a1);
  k_conv2<<<dim3(512, 2), 256, 0, stream>>>(a1, w2t, b2, a2);
  // a1 now dead; everything below may write region0

  hipMemsetAsync(comb0 + 256 * 32, 0, (size_t)512 * 32 * 4, stream);
  hipMemsetAsync(comb1 + 512 * 32, 0, (size_t)512 * 32 * 4, stream);
  hipMemsetAsync(c0, 0, (size_t)2 * 512 * 32 * 4, stream);
  hipMemsetAsync(bar, 0, sizeof(int), stream);

  k_conv3<<<dim3(512, 8), 256, 0, stream>>>(a2, w3t, b3, comb0);

  k_pack<<<dim3(24, 16), 256, 0, stream>>>(
      (const float*)d_in[7], (const float*)d_in[9],
      (const float*)d_in[11], (const float*)d_in[13], p0, 768);
  k_pack<<<dim3(32, 16), 256, 0, stream>>>(
      (const float*)d_in[15], (const float*)d_in[17],
      (const float*)d_in[19], (const float*)d_in[21], p1, 1024);

  Coop2Args ca;
  ca.comb0 = comb0; ca.comb1 = comb1;
  ca.p0 = p0; ca.p1 = p1;
  ca.b00 = (const float*)d_in[8];  ca.b01 = (const float*)d_in[10];
  ca.b02 = (const float*)d_in[12]; ca.b03 = (const float*)d_in[14];
  ca.b10 = (const float*)d_in[16]; ca.b11 = (const float*)d_in[18];
  ca.b12 = (const float*)d_in[20]; ca.b13 = (const float*)d_in[22];
  ca.bar = bar;
  void* kargs[] = {&ca};
  hipError_t cerr = hipLaunchCooperativeKernel(
      (void*)k_lstm_coop2, dim3(256), dim3(512), kargs, COOP2_LDS_BYTES, stream);

  if (cerr != hipSuccess) {
    auto L0 = [&](int t) {
      SArgs a;
      a.comb = comb0 + (size_t)t * C0;
      a.pw = p0;
      a.houtA = comb0 + (size_t)(t + 1) * C0 + 256 * 32;
      a.houtB = comb1 + (size_t)t * C1;
      a.cT = c0;
      a.bf = (const float*)d_in[8];  a.bi = (const float*)d_in[10];
      a.bg = (const float*)d_in[12]; a.bo = (const float*)d_in[14];
      return a;
    };
    auto L1 = [&](int t) {
      SArgs a;
      a.comb = comb1 + (size_t)t * C1;
      a.pw = p1;
      a.houtA = comb1 + (size_t)(t + 1) * C1 + 512 * 32;
      a.houtB = a.houtA;
      a.cT = c1;
      a.bf = (const float*)d_in[16]; a.bi = (const float*)d_in[18];
      a.bg = (const float*)d_in[20]; a.bo = (const float*)d_in[22];
      return a;
    };
    k_lstm_s0<<<512, 512, 0, stream>>>(L0(0));
    for (int p = 0; p < 15; ++p)
      k_lstm_spair<<<1024, 512, 0, stream>>>(L0(p + 1), L1(p));
    k_lstm_s1<<<512, 512, 0, stream>>>(L1(15));
  }

  k_cls<<<32, 128, 0, stream>>>(comb1 + (size_t)16 * C1 + 512 * 32,
                                cw1, cb1, cw2, cb2, cw3, cb3, (float*)d_out);
}